// Round 7
// baseline (281.501 us; speedup 1.0000x reference)
//
#include <hip/hip_runtime.h>
#include <hip/hip_bf16.h>
#include <stdint.h>

#define S_LEN 2048
#define EMB   1024
#define NHEAD 16
#define HDIM  64
#define BATCH 2

typedef __bf16 bf16x8 __attribute__((ext_vector_type(8)));
typedef float  f32x4  __attribute__((ext_vector_type(4)));

// async global->LDS, 16B per lane; LDS dest = wave-uniform base + lane*16
__device__ __forceinline__ void gll16(const void* g, void* l) {
  __builtin_amdgcn_global_load_lds(
      (const __attribute__((address_space(1))) void*)g,
      (__attribute__((address_space(3))) void*)l,
      16, 0, 0);
}

__device__ __forceinline__ bf16x8 pack_bf16(f32x4 a, f32x4 b) {
  __hip_bfloat16 tmp[8];
#pragma unroll
  for (int k = 0; k < 4; ++k) { tmp[k] = __float2bfloat16(a[k]); tmp[4 + k] = __float2bfloat16(b[k]); }
  return *(bf16x8*)tmp;
}

// ---------------- kernel 1: QKV GEMM (fp32 in) + fused mask-flag blocks -----
// blocks [0,1024): mask tile flags (64q x 128k).  blocks [1024,1792): GEMM.
// GEMM: C = A @ W^T + bias, 128x128 tiles, BK=32, fp32 staged, cvt on frag read.
// z=0 -> Q (scale log2e/8, [b,h,s,d]); z=1 -> K ([b,h,s,d]); z=2 -> V frag-packed.
__global__ void __launch_bounds__(256, 3)
qkv_flags_kernel(const float* __restrict__ A0, const float* __restrict__ A1,
                 const float* __restrict__ A2,
                 const float* __restrict__ W0, const float* __restrict__ W1,
                 const float* __restrict__ W2,
                 const float* __restrict__ b0, const float* __restrict__ b1,
                 const float* __restrict__ b2,
                 __hip_bfloat16* __restrict__ O0, __hip_bfloat16* __restrict__ O1,
                 __hip_bfloat16* __restrict__ O2,
                 const int* __restrict__ mask, unsigned* __restrict__ flags) {
  __shared__ __align__(16) float Asf[128 * 32];
  __shared__ __align__(16) float Bsf[128 * 32];
  __shared__ unsigned long long bw[4];

  const int L = blockIdx.x;
  const int t = threadIdx.x;

  if (L < 1024) {  // ---- mask tile flags ----
    const int kt = L & 15, qt = (L >> 4) & 31, b = L >> 9;
    const int* base = mask + ((size_t)b * S_LEN + (size_t)qt * 64) * S_LEN + (size_t)kt * 128;
    int ok = 1;
#pragma unroll
    for (int p = 0; p < 8; ++p) {
      int idx = p * 256 + t;
      int row = idx >> 5, c4 = idx & 31;
      const int4 v = *(const int4*)(base + (size_t)row * S_LEN + c4 * 4);
      ok &= (v.x != 0) & (v.y != 0) & (v.z != 0) & (v.w != 0);
    }
    unsigned long long bl = __ballot(ok);
    bw[t >> 6] = bl;
    __syncthreads();
    if (t == 0) {
      unsigned all = ((bw[0] & bw[1] & bw[2] & bw[3]) == ~0ull) ? 1u : 0u;
      flags[((size_t)b * 32 + qt) * 16 + kt] = all;
    }
    return;
  }

  // ---- GEMM path ----
  const int G = L - 1024;
  const int m0 = (G & 31) * 128;        // m-tile mod 8 == XCD (A reuse on-XCD)
  const int n0 = ((G >> 5) & 7) * 128;
  const int z  = G >> 8;

  const float* A  = (z == 0) ? A0 : ((z == 1) ? A1 : A2);
  const float* W  = (z == 0) ? W0 : ((z == 1) ? W1 : W2);
  const float* bi = (z == 0) ? b0 : ((z == 1) ? b1 : b2);
  __hip_bfloat16* O = (z == 0) ? O0 : ((z == 1) ? O1 : O2);

  const int w = t >> 6, lane = t & 63, quad = lane >> 4, l15 = lane & 15;
  const int wr = w >> 1, wc = w & 1;

  f32x4 acc[4][4];
#pragma unroll
  for (int i = 0; i < 4; ++i)
#pragma unroll
    for (int j = 0; j < 4; ++j) acc[i][j] = (f32x4)0.0f;

  // staging: row = rnd*32 + t/8, 16B block (t&7) holds logical block (t&7)^(row&7)
  const int srow = t >> 3;
  const int scb  = (t & 7) ^ (srow & 7);
  const float* Ap = A + (size_t)(m0 + srow) * EMB + scb * 4;
  const float* Wp = W + (size_t)(n0 + srow) * EMB + scb * 4;

  for (int k0 = 0; k0 < EMB; k0 += 32) {
    __syncthreads();
#pragma unroll
    for (int rnd = 0; rnd < 4; ++rnd) {
      gll16(Ap + (size_t)(rnd * 32) * EMB + k0, &Asf[(rnd * 256 + (w << 6)) * 4]);
      gll16(Wp + (size_t)(rnd * 32) * EMB + k0, &Bsf[(rnd * 256 + (w << 6)) * 4]);
    }
    __syncthreads();

    bf16x8 af[4], bfr[4];
#pragma unroll
    for (int i = 0; i < 4; ++i) {
      const int ra = wr * 64 + i * 16 + l15;
      f32x4 a0 = *(const f32x4*)&Asf[ra * 32 + ((((quad << 1)) ^ (ra & 7)) << 2)];
      f32x4 a1 = *(const f32x4*)&Asf[ra * 32 + ((((quad << 1) | 1) ^ (ra & 7)) << 2)];
      af[i] = pack_bf16(a0, a1);
    }
#pragma unroll
    for (int j = 0; j < 4; ++j) {
      const int rb_ = wc * 64 + j * 16 + l15;
      f32x4 b0v = *(const f32x4*)&Bsf[rb_ * 32 + ((((quad << 1)) ^ (rb_ & 7)) << 2)];
      f32x4 b1v = *(const f32x4*)&Bsf[rb_ * 32 + ((((quad << 1) | 1) ^ (rb_ & 7)) << 2)];
      bfr[j] = pack_bf16(b0v, b1v);
    }
#pragma unroll
    for (int i = 0; i < 4; ++i)
#pragma unroll
      for (int j = 0; j < 4; ++j)
        acc[i][j] = __builtin_amdgcn_mfma_f32_16x16x32_bf16(af[i], bfr[j], acc[i][j], 0, 0, 0);
  }

#pragma unroll
  for (int j = 0; j < 4; ++j) {
    const int ng = n0 + wc * 64 + j * 16 + l15;
    const float bb = bi[ng];
    const int h = ng >> 6, d = ng & 63;
#pragma unroll
    for (int i = 0; i < 4; ++i) {
#pragma unroll
      for (int r = 0; r < 4; ++r) {
        const int mg = m0 + wr * 64 + i * 16 + quad * 4 + r;
        const int b = mg >> 11, s = mg & 2047;
        float v = acc[i][j][r] + bb;
        if (z == 0) {        // Q, pre-scaled by log2e/8 so flash uses raw exp2
          O[(((size_t)b * NHEAD + h) * S_LEN + s) * HDIM + d] =
              __float2bfloat16(v * (0.125f * 1.4426950408889634f));
        } else if (z == 1) { // K
          O[(((size_t)b * NHEAD + h) * S_LEN + s) * HDIM + d] = __float2bfloat16(v);
        } else {             // V frag-packed (matches flash PV B-operand layout)
          const size_t idx = (size_t)(b * NHEAD + h) * 131072 + (size_t)(s >> 7) * 8192 +
                             (size_t)((((s >> 5) & 3) * 4 + ((s >> 2) & 3)) * 64 + d) * 8 +
                             ((s >> 4) & 1) * 4 + (s & 3);
          O[idx] = __float2bfloat16(v);
        }
      }
    }
  }
}

// ---------------- kernel 3: output projection, 64x128, BK=32, W fp32 --------
__global__ void __launch_bounds__(256, 2)
gemm_o_kernel(const __hip_bfloat16* __restrict__ A, const float* __restrict__ W,
              const float* __restrict__ bi, float* __restrict__ O) {
  __shared__ __align__(16) __hip_bfloat16 Asb[64 * 32];  // bf16, 64B rows (2-way free)
  __shared__ __align__(16) float Bsf[128 * 32];          // fp32, swizzled
  const int L = blockIdx.x;
  const int m0 = (L & 63) * 64;    // m-tile mod 8 == XCD
  const int n0 = (L >> 6) * 128;
  const int t = threadIdx.x;
  const int w = t >> 6, lane = t & 63, quad = lane >> 4, l15 = lane & 15;
  const int wr = w >> 1, wc = w & 1;

  f32x4 acc[2][4];
#pragma unroll
  for (int i = 0; i < 2; ++i)
#pragma unroll
    for (int j = 0; j < 4; ++j) acc[i][j] = (f32x4)0.0f;

  const int srW = t >> 3;
  const int scbW = (t & 7) ^ (srW & 7);
  const __hip_bfloat16* Ap = A + (size_t)(m0 + (t >> 2)) * EMB + (t & 3) * 8;
  const float* Wp = W + (size_t)(n0 + srW) * EMB + scbW * 4;

  for (int k0 = 0; k0 < EMB; k0 += 32) {
    __syncthreads();
    gll16(Ap + k0, &Asb[(w << 6) * 8]);
#pragma unroll
    for (int rnd = 0; rnd < 4; ++rnd)
      gll16(Wp + (size_t)(rnd * 32) * EMB + k0, &Bsf[(rnd * 256 + (w << 6)) * 4]);
    __syncthreads();

    bf16x8 af[2], bfr[4];
#pragma unroll
    for (int i = 0; i < 2; ++i)
      af[i] = *(const bf16x8*)&Asb[(wr * 32 + i * 16 + l15) * 32 + quad * 8];
#pragma unroll
    for (int j = 0; j < 4; ++j) {
      const int rb_ = wc * 64 + j * 16 + l15;
      f32x4 b0v = *(const f32x4*)&Bsf[rb_ * 32 + ((((quad << 1)) ^ (rb_ & 7)) << 2)];
      f32x4 b1v = *(const f32x4*)&Bsf[rb_ * 32 + ((((quad << 1) | 1) ^ (rb_ & 7)) << 2)];
      bfr[j] = pack_bf16(b0v, b1v);
    }
#pragma unroll
    for (int i = 0; i < 2; ++i)
#pragma unroll
      for (int j = 0; j < 4; ++j)
        acc[i][j] = __builtin_amdgcn_mfma_f32_16x16x32_bf16(af[i], bfr[j], acc[i][j], 0, 0, 0);
  }

#pragma unroll
  for (int j = 0; j < 4; ++j) {
    const int ng = n0 + wc * 64 + j * 16 + l15;
    const float bb = bi[ng];
#pragma unroll
    for (int i = 0; i < 2; ++i) {
#pragma unroll
      for (int r = 0; r < 4; ++r) {
        const int mg = m0 + wr * 32 + i * 16 + quad * 4 + r;
        O[(size_t)mg * EMB + ng] = acc[i][j][r] + bb;
      }
    }
  }
}

// ---------------- kernel 2: flash, 64-q blocks, split-K waves, ones-MFMA ----
// 4 waves: wq=w&1 picks 32-q band, khalf=w>>1 picks 64-key half. lsum computed
// by an extra PV MFMA with B=ones (C rows quad*4+r == output rows, no shuffles).
__global__ void __launch_bounds__(256, 4)
flash_kernel(const __hip_bfloat16* __restrict__ qws, const __hip_bfloat16* __restrict__ kws,
             const __hip_bfloat16* __restrict__ vpk, const int* __restrict__ responses,
             const int* __restrict__ mask, const float* __restrict__ Wm,
             const unsigned* __restrict__ flags, __hip_bfloat16* __restrict__ att) {
  __shared__ __align__(16) unsigned char smem[32768];  // Ks(16K)+Vs(16K); f32 merge overlay
  __shared__ unsigned char rb[S_LEN];

  __hip_bfloat16* Ks = (__hip_bfloat16*)smem;
  __hip_bfloat16* Vs = (__hip_bfloat16*)(smem + 16384);
  float* sm  = (float*)smem;
  float* lsm = sm + 4096;

  const int t = threadIdx.x;
  const int w = t >> 6, lane = t & 63, quad = lane >> 4, l15 = lane & 15;
  const int L = blockIdx.x;
  const int bh = L & 31;          // bh mod 8 == XCD
  const int qt = L >> 5;          // 32 x 64-q tiles
  const int b = bh >> 4, h = bh & 15;
  const int q0 = qt * 64;
  const int wq = w & 1, khalf = w >> 1;

#pragma unroll
  for (int i = 0; i < 8; ++i)
    rb[i * 256 + t] = (unsigned char)responses[b * S_LEN + i * 256 + t];

  const __hip_bfloat16* qbase = qws + ((size_t)bh * S_LEN + q0 + wq * 32) * HDIM;
  bf16x8 qf[2][2];
#pragma unroll
  for (int qg = 0; qg < 2; ++qg)
#pragma unroll
    for (int ks = 0; ks < 2; ++ks)
      qf[qg][ks] =
          *(const bf16x8*)(qbase + (size_t)(qg * 16 + l15) * HDIM + ks * 32 + quad * 8);

  const float c = Wm[h] * (0.0625f * 1.4426950408889634f);  // Wm/16 * log2e
  float A2[2];
#pragma unroll
  for (int qg = 0; qg < 2; ++qg)
    A2[qg] = 2.0f * c * (float)responses[b * S_LEN + q0 + wq * 32 + qg * 16 + l15];

  const __hip_bfloat16* kptr = kws + ((size_t)bh * S_LEN + (t >> 3)) * HDIM +
                               (((t & 7) ^ ((t >> 3) & 7)) << 3);
  const __hip_bfloat16* vptr = vpk + (size_t)bh * 131072 + (size_t)t * 8;

  bf16x8 onesf;
  {
    __hip_bfloat16 one = __float2bfloat16(1.0f);
#pragma unroll
    for (int k = 0; k < 8; ++k) ((__hip_bfloat16*)&onesf)[k] = one;
  }

  f32x4 acc_l[2];
  f32x4 acc_o[2][4];
#pragma unroll
  for (int qg = 0; qg < 2; ++qg) {
    acc_l[qg] = (f32x4)0.0f;
#pragma unroll
    for (int dt = 0; dt < 4; ++dt) acc_o[qg][dt] = (f32x4)0.0f;
  }

  for (int kt = 0; kt < S_LEN / 128; ++kt) {
    __syncthreads();  // A: prior QK/PV reads of Ks/Vs complete
#pragma unroll
    for (int p = 0; p < 4; ++p) {
      gll16(kptr + p * 32 * HDIM, &Ks[(p * 256 + (w << 6)) * 8]);
      gll16(vptr + p * 2048,      &Vs[(p * 256 + (w << 6)) * 8]);
    }
    kptr += 128 * HDIM;
    vptr += 8192;
    __syncthreads();  // B: staging complete

    const unsigned fl = flags[((size_t)b * 32 + qt) * 16 + kt];

    bf16x8 pfr[2][2];  // [qg][32-key pair-group]
#pragma unroll
    for (int ct = 0; ct < 4; ++ct) {
      const int rowk = khalf * 64 + ct * 16 + l15;
      bf16x8 kf0 = *(const bf16x8*)&Ks[rowk * 64 + ((quad ^ (l15 & 7)) << 3)];
      bf16x8 kf1 = *(const bf16x8*)&Ks[rowk * 64 + (((4 + quad) ^ (l15 & 7)) << 3)];
      const unsigned ru = *(const unsigned*)&rb[kt * 128 + khalf * 64 + ct * 16 + quad * 4];
#pragma unroll
      for (int qg = 0; qg < 2; ++qg) {
        f32x4 sc = __builtin_amdgcn_mfma_f32_16x16x32_bf16(kf0, qf[qg][0], (f32x4)0.0f, 0, 0, 0);
        sc = __builtin_amdgcn_mfma_f32_16x16x32_bf16(kf1, qf[qg][1], sc, 0, 0, 0);
        __hip_bfloat16 pb[4];
#pragma unroll
        for (int r = 0; r < 4; ++r) {
          const float rkf = (float)((ru >> (8 * r)) & 255u);
          const float sb = fmaf(rkf, fmaf(-c, rkf, A2[qg]), sc[r]);
          float p = __builtin_amdgcn_exp2f(sb);
          if (!fl) {  // slow path (all-ones mask never takes it)
            int mq = mask[((size_t)b * S_LEN + q0 + wq * 32 + qg * 16 + l15) * S_LEN +
                          kt * 128 + khalf * 64 + ct * 16 + quad * 4 + r];
            p = mq ? p : 0.0f;
          }
          pb[r] = __float2bfloat16(p);
        }
        __hip_bfloat16* half = (__hip_bfloat16*)&pfr[qg][ct >> 1] + (ct & 1) * 4;
        half[0] = pb[0]; half[1] = pb[1]; half[2] = pb[2]; half[3] = pb[3];
      }
    }

    // PV + lsum (ones-frag): vv loaded once per (ct2,dt), reused across qg
#pragma unroll
    for (int ct2 = 0; ct2 < 2; ++ct2) {
      const int g2 = khalf * 2 + ct2;
#pragma unroll
      for (int qg = 0; qg < 2; ++qg)
        acc_l[qg] = __builtin_amdgcn_mfma_f32_16x16x32_bf16(pfr[qg][ct2], onesf, acc_l[qg], 0, 0, 0);
#pragma unroll
      for (int dt = 0; dt < 4; ++dt) {
        bf16x8 vv = *(const bf16x8*)&Vs[(((g2 << 2) + quad) * 64 + (dt << 4) + l15) << 3];
#pragma unroll
        for (int qg = 0; qg < 2; ++qg)
          acc_o[qg][dt] =
              __builtin_amdgcn_mfma_f32_16x16x32_bf16(pfr[qg][ct2], vv, acc_o[qg][dt], 0, 0, 0);
      }
    }
  }

  // ---- merge key-halves (exact fp32 adds), normalize, store ----------------
  __syncthreads();  // staging region free; reuse as f32 scratch
  if (khalf == 0) {
#pragma unroll
    for (int qg = 0; qg < 2; ++qg) {
#pragma unroll
      for (int dt = 0; dt < 4; ++dt)
        *(f32x4*)&sm[((((wq << 1) + qg) << 2) + dt) * 256 + lane * 4] = acc_o[qg][dt];
      if (l15 == 0) *(f32x4*)&lsm[((wq << 1) + qg) * 16 + quad * 4] = acc_l[qg];
    }
  }
  __syncthreads();
  if (khalf == 1) {
#pragma unroll
    for (int qg = 0; qg < 2; ++qg) {
      acc_l[qg] += *(const f32x4*)&lsm[((wq << 1) + qg) * 16 + quad * 4];
      float inv[4];
#pragma unroll
      for (int r = 0; r < 4; ++r) inv[r] = 1.0f / acc_l[qg][r];
#pragma unroll
      for (int dt = 0; dt < 4; ++dt) {
        acc_o[qg][dt] += *(const f32x4*)&sm[((((wq << 1) + qg) << 2) + dt) * 256 + lane * 4];
#pragma unroll
        for (int r = 0; r < 4; ++r)
          att[((size_t)b * S_LEN + q0 + wq * 32 + qg * 16 + quad * 4 + r) * EMB +
              h * HDIM + dt * 16 + l15] = __float2bfloat16(acc_o[qg][dt][r] * inv[r]);
      }
    }
  }
}

// ---------------------------------------------------------------------------
extern "C" void kernel_launch(void* const* d_in, const int* in_sizes, int n_in,
                              void* d_out, int out_size, void* d_ws, size_t ws_size,
                              hipStream_t stream) {
  const float* query = (const float*)d_in[0];
  const float* key_  = (const float*)d_in[1];
  const float* value = (const float*)d_in[2];
  const int* responses = (const int*)d_in[3];
  const int* mask      = (const int*)d_in[4];
  const float* Wq = (const float*)d_in[5];
  const float* bq = (const float*)d_in[6];
  const float* Wk = (const float*)d_in[7];
  const float* bk = (const float*)d_in[8];
  const float* Wv = (const float*)d_in[9];
  const float* bv = (const float*)d_in[10];
  const float* Wo = (const float*)d_in[11];
  const float* bo = (const float*)d_in[12];
  const float* Wm = (const float*)d_in[13];
  // d_in[14] (bm): per-row constant under softmax -> exactly cancels; unused.

  __hip_bfloat16* ws = (__hip_bfloat16*)d_ws;
  const size_t NTOK = (size_t)BATCH * S_LEN * EMB;  // 4 Mi elements
  __hip_bfloat16* qws  = ws;
  __hip_bfloat16* kws  = ws + NTOK;
  __hip_bfloat16* vpk  = ws + 2 * NTOK;
  __hip_bfloat16* att  = ws + 3 * NTOK;
  unsigned* flags      = (unsigned*)(ws + 4 * NTOK);
  float* out           = (float*)d_out;

  qkv_flags_kernel<<<1792, 256, 0, stream>>>(query, key_, value, Wq, Wk, Wv,
                                             bq, bk, bv, qws, kws, vpk, mask, flags);
  flash_kernel<<<1024, 256, 0, stream>>>(qws, kws, vpk, responses, mask,
                                         Wm, flags, att);
  gemm_o_kernel<<<512, 256, 0, stream>>>(att, Wo, bo, out);
}